// Round 8
// baseline (171.435 us; speedup 1.0000x reference)
//
#include <hip/hip_runtime.h>
#include <stdint.h>

#define N_CODES 65536
#define CB_DIM 8
#define B_ROWS 16
#define X_COLS 2048
#define M_ROWS 4096            // 16*2048/8
#define RPB 4                  // rows per block in argmin kernel (r8: 8->4 for 2x occupancy)
#define THREADS 256

// workspace byte offsets (all 16B-aligned)
#define WS_SCALE 0             // 16 f32
#define WS_IDX   256           // 4096 i32
#define WS_NU    16640         // 32768 f32  (nu = -2*x/scale, flat, x-layout)

// distance + min-track for one code against RPB SGPR-resident rows.
// each fma reads exactly one SGPR (nu) -> v_fma_f32 vD, s, v, vD (legal).
#define CODE_BODY(C0, C1, NIDX)                                            \
    {                                                                      \
        float hn = (C0).x * (C0).x;                                        \
        hn = fmaf((C0).y, (C0).y, hn);                                     \
        hn = fmaf((C0).z, (C0).z, hn);                                     \
        hn = fmaf((C0).w, (C0).w, hn);                                     \
        hn = fmaf((C1).x, (C1).x, hn);                                     \
        hn = fmaf((C1).y, (C1).y, hn);                                     \
        hn = fmaf((C1).z, (C1).z, hn);                                     \
        hn = fmaf((C1).w, (C1).w, hn);                                     \
        _Pragma("unroll")                                                  \
        for (int r = 0; r < RPB; r++) {                                    \
            float d = hn;                                                  \
            d = fmaf(nu[r * 8 + 0], (C0).x, d);                            \
            d = fmaf(nu[r * 8 + 1], (C0).y, d);                            \
            d = fmaf(nu[r * 8 + 2], (C0).z, d);                            \
            d = fmaf(nu[r * 8 + 3], (C0).w, d);                            \
            d = fmaf(nu[r * 8 + 4], (C1).x, d);                            \
            d = fmaf(nu[r * 8 + 5], (C1).y, d);                            \
            d = fmaf(nu[r * 8 + 6], (C1).z, d);                            \
            d = fmaf(nu[r * 8 + 7], (C1).w, d);                            \
            if (d < best[r]) { best[r] = d; bidx[r] = (NIDX); }            \
        }                                                                  \
    }

// ---------------- prep: per-row scale + nu = -2*x/scale ----------------
__global__ __launch_bounds__(256) void prep_kernel(const float* __restrict__ x,
                                                   float* __restrict__ scale_out,
                                                   float* __restrict__ nu_out) {
    int row = blockIdx.x;
    int tid = threadIdx.x;
    const float4* xv = (const float4*)(x + row * X_COLS);
    float4 q0 = xv[tid];
    float4 q1 = xv[tid + 256];
    float s = fabsf(q0.x) + fabsf(q0.y) + fabsf(q0.z) + fabsf(q0.w)
            + fabsf(q1.x) + fabsf(q1.y) + fabsf(q1.z) + fabsf(q1.w);
    #pragma unroll
    for (int off = 32; off > 0; off >>= 1) s += __shfl_down(s, off, 64);
    __shared__ float ls[4];
    __shared__ float scale_sh;
    int wave = tid >> 6, lane = tid & 63;
    if (lane == 0) ls[wave] = s;
    __syncthreads();
    if (tid == 0) {
        float t = (ls[0] + ls[1] + ls[2] + ls[3]) * (1.0f / (float)X_COLS);
        scale_sh = t;
        scale_out[row] = t;
    }
    __syncthreads();
    float sc = scale_sh;

    // nu = -2*(x/scale); finalize recovers u-sums as -0.5*sum(nu), bit-exact
    float4 n0, n1;
    n0.x = -2.0f * (q0.x / sc); n0.y = -2.0f * (q0.y / sc);
    n0.z = -2.0f * (q0.z / sc); n0.w = -2.0f * (q0.w / sc);
    n1.x = -2.0f * (q1.x / sc); n1.y = -2.0f * (q1.y / sc);
    n1.z = -2.0f * (q1.z / sc); n1.w = -2.0f * (q1.w / sc);
    float4* nv = (float4*)(nu_out + row * X_COLS);
    nv[tid] = n0;
    nv[tid + 256] = n1;
}

// ---------------- argmin: 4 rows/block, 1024 blocks ----------------
// nu via block-uniform loads -> s_load -> SGPR-resident (verified r7:
// SGPR_Count 96). r7 failure: RPB=8 @ 512 blocks = 2 waves/SIMD and the
// allocator squeezed VGPRs to 36, killing the prefetch regs -> latency-
// bound. RPB=4 @ 1024 blocks = 4 waves/SIMD doubles TLP and the smaller
// body (~46 VGPR) keeps its prefetch under the allocator's squeeze target.
__global__ __launch_bounds__(256, 4) void argmin_kernel(const float* __restrict__ cb,
                                                        const float* __restrict__ nu_g,
                                                        int* __restrict__ indices) {
    int tid = threadIdx.x;
    int m0 = blockIdx.x * RPB;

    const float* nup = nu_g + (size_t)m0 * CB_DIM;     // block-uniform
    float nu[RPB * CB_DIM];
    #pragma unroll
    for (int i = 0; i < RPB * CB_DIM; i++) nu[i] = nup[i];

    float best[RPB];
    int   bidx[RPB];
    #pragma unroll
    for (int r = 0; r < RPB; r++) { best[r] = 3.4e38f; bidx[r] = 0; }

    // ---- hot loop: 2 codes/iter, register double-prefetch, peeled tail ----
    const float4* cp = (const float4*)cb;
    float4 a0 = cp[2 * tid],             a1 = cp[2 * tid + 1];
    float4 b0 = cp[2 * (tid + THREADS)], b1 = cp[2 * (tid + THREADS) + 1];

    int n = tid;
    for (int k = 0; k < 127; k++, n += 2 * THREADS) {
        float4 pa0 = cp[2 * (n + 2 * THREADS)], pa1 = cp[2 * (n + 2 * THREADS) + 1];
        CODE_BODY(a0, a1, n)
        float4 pb0 = cp[2 * (n + 3 * THREADS)], pb1 = cp[2 * (n + 3 * THREADS) + 1];
        CODE_BODY(b0, b1, n + THREADS)
        a0 = pa0; a1 = pa1; b0 = pb0; b1 = pb1;
    }
    CODE_BODY(a0, a1, n)
    CODE_BODY(b0, b1, n + THREADS)

    // ---- cross-thread reduce: (sortable(dist)<<32)|idx, u64-min ----
    __shared__ unsigned long long red[RPB][THREADS];   // 8 KB
    #pragma unroll
    for (int r = 0; r < RPB; r++) {
        unsigned int b = __float_as_uint(best[r]);
        unsigned int k = b ^ ((unsigned int)((int)b >> 31) | 0x80000000u);
        red[r][tid] = ((unsigned long long)k << 32) | (unsigned int)bidx[r];
    }
    for (int t = THREADS / 2; t > 0; t >>= 1) {
        __syncthreads();
        if (tid < t) {
            #pragma unroll
            for (int r = 0; r < RPB; r++) {
                unsigned long long a = red[r][tid], c = red[r][tid + t];
                if (c < a) red[r][tid] = c;
            }
        }
    }
    __syncthreads();
    if (tid < RPB) {
        indices[m0 + tid] = (int)(red[tid][0] & 0xFFFFFFFFull);
    }
}

// ---------------- finalize: segment-mean + gather + rescale ----------------
// Each output row scans all 4096 indices (LDS-resident, int4-vectorized) and
// averages matching nu-rows; u-sum = -0.5 * nu-sum (exact, pow2 scale).
// grid 128 blocks x 256: 32 rows/block, 8 threads/row, 512 indices/thread.
__global__ __launch_bounds__(256) void finalize_kernel(const int* __restrict__ indices,
                                                       const float* __restrict__ nu_g,
                                                       const float* __restrict__ scale,
                                                       float* __restrict__ out) {
    __shared__ int idx_sh[M_ROWS];                     // 16 KB
    int tid = threadIdx.x;
    {
        const int4* ig = (const int4*)indices;
        int4* is = (int4*)idx_sh;
        for (int i = tid; i < M_ROWS / 4; i += 256) is[i] = ig[i];
    }
    __syncthreads();

    int r = tid >> 3, p = tid & 7;                     // 32 rows, 8 parts
    int m = blockIdx.x * 32 + r;
    int my = idx_sh[m];

    float cnt = 0.f;
    float sum[CB_DIM];
    #pragma unroll
    for (int k = 0; k < CB_DIM; k++) sum[k] = 0.f;

    const float4* uv = (const float4*)nu_g;
    const int4* is = (const int4*)(idx_sh + p * 512);
    #pragma unroll 2
    for (int q = 0; q < 128; q++) {
        int4 w = is[q];
        int j = p * 512 + 4 * q;
        if (w.x == my) {
            float4 v0 = uv[2 * j], v1 = uv[2 * j + 1];
            cnt += 1.f;
            sum[0] += v0.x; sum[1] += v0.y; sum[2] += v0.z; sum[3] += v0.w;
            sum[4] += v1.x; sum[5] += v1.y; sum[6] += v1.z; sum[7] += v1.w;
        }
        if (w.y == my) {
            float4 v0 = uv[2 * j + 2], v1 = uv[2 * j + 3];
            cnt += 1.f;
            sum[0] += v0.x; sum[1] += v0.y; sum[2] += v0.z; sum[3] += v0.w;
            sum[4] += v1.x; sum[5] += v1.y; sum[6] += v1.z; sum[7] += v1.w;
        }
        if (w.z == my) {
            float4 v0 = uv[2 * j + 4], v1 = uv[2 * j + 5];
            cnt += 1.f;
            sum[0] += v0.x; sum[1] += v0.y; sum[2] += v0.z; sum[3] += v0.w;
            sum[4] += v1.x; sum[5] += v1.y; sum[6] += v1.z; sum[7] += v1.w;
        }
        if (w.w == my) {
            float4 v0 = uv[2 * j + 6], v1 = uv[2 * j + 7];
            cnt += 1.f;
            sum[0] += v0.x; sum[1] += v0.y; sum[2] += v0.z; sum[3] += v0.w;
            sum[4] += v1.x; sum[5] += v1.y; sum[6] += v1.z; sum[7] += v1.w;
        }
    }

    // reduce across the 8 lanes of this row (contiguous lanes within a wave)
    #pragma unroll
    for (int off = 1; off < 8; off <<= 1) {
        cnt += __shfl_xor(cnt, off, 64);
        #pragma unroll
        for (int k = 0; k < CB_DIM; k++) sum[k] += __shfl_xor(sum[k], off, 64);
    }

    if (p == 0) {
        float c = cnt < 1.f ? 1.f : cnt;               // matches clip(counts,1)
        float sc = scale[m >> 8];
        float inv = -0.5f / c;                         // u-sum = -0.5*nu-sum
        float4 o0 = make_float4(sc * (sum[0] * inv), sc * (sum[1] * inv),
                                sc * (sum[2] * inv), sc * (sum[3] * inv));
        float4 o1 = make_float4(sc * (sum[4] * inv), sc * (sum[5] * inv),
                                sc * (sum[6] * inv), sc * (sum[7] * inv));
        float4* op = (float4*)(out + (size_t)m * CB_DIM);
        op[0] = o0;
        op[1] = o1;
    }
}

extern "C" void kernel_launch(void* const* d_in, const int* in_sizes, int n_in,
                              void* d_out, int out_size, void* d_ws, size_t ws_size,
                              hipStream_t stream) {
    const float* x  = (const float*)d_in[0];           // [16,2048]
    const float* cb = (const float*)d_in[1];           // [65536,8]
    char* ws = (char*)d_ws;
    float* scale   = (float*)(ws + WS_SCALE);
    int*   indices = (int*)(ws + WS_IDX);
    float* nu      = (float*)(ws + WS_NU);
    float* out     = (float*)d_out;

    prep_kernel    <<<B_ROWS, 256, 0, stream>>>(x, scale, nu);
    argmin_kernel  <<<M_ROWS / RPB, 256, 0, stream>>>(cb, nu, indices);
    finalize_kernel<<<M_ROWS / 32, 256, 0, stream>>>(indices, nu, scale, out);
}

// Round 9
// 168.061 us; speedup vs baseline: 1.0201x; 1.0201x over previous
//
#include <hip/hip_runtime.h>
#include <stdint.h>

#define N_CODES 65536
#define CB_DIM 8
#define B_ROWS 16
#define X_COLS 2048
#define M_ROWS 4096            // 16*2048/8
#define RPB 8                  // rows per block (r9: back to 8 — halves per-CU codebook traffic)
#define THREADS 256

// workspace byte offsets (all 16B-aligned)
#define WS_SCALE 0             // 16 f32
#define WS_IDX   256           // 4096 i32
#define WS_NU    16640         // 32768 f32  (nu = -2*x/scale, flat, x-layout)

// distance + min-track for one code against RPB SGPR-resident rows.
// each fma reads exactly one SGPR (nu) -> v_fma_f32 vD, s, v, vD (legal).
#define CODE_BODY(C0, C1, NIDX)                                            \
    {                                                                      \
        float hn = (C0).x * (C0).x;                                        \
        hn = fmaf((C0).y, (C0).y, hn);                                     \
        hn = fmaf((C0).z, (C0).z, hn);                                     \
        hn = fmaf((C0).w, (C0).w, hn);                                     \
        hn = fmaf((C1).x, (C1).x, hn);                                     \
        hn = fmaf((C1).y, (C1).y, hn);                                     \
        hn = fmaf((C1).z, (C1).z, hn);                                     \
        hn = fmaf((C1).w, (C1).w, hn);                                     \
        _Pragma("unroll")                                                  \
        for (int r = 0; r < RPB; r++) {                                    \
            float d = hn;                                                  \
            d = fmaf(nu[r * 8 + 0], (C0).x, d);                            \
            d = fmaf(nu[r * 8 + 1], (C0).y, d);                            \
            d = fmaf(nu[r * 8 + 2], (C0).z, d);                            \
            d = fmaf(nu[r * 8 + 3], (C0).w, d);                            \
            d = fmaf(nu[r * 8 + 4], (C1).x, d);                            \
            d = fmaf(nu[r * 8 + 5], (C1).y, d);                            \
            d = fmaf(nu[r * 8 + 6], (C1).z, d);                            \
            d = fmaf(nu[r * 8 + 7], (C1).w, d);                            \
            if (d < best[r]) { best[r] = d; bidx[r] = (NIDX); }            \
        }                                                                  \
    }

// ---------------- prep: per-row scale + nu = -2*x/scale ----------------
__global__ __launch_bounds__(256) void prep_kernel(const float* __restrict__ x,
                                                   float* __restrict__ scale_out,
                                                   float* __restrict__ nu_out) {
    int row = blockIdx.x;
    int tid = threadIdx.x;
    const float4* xv = (const float4*)(x + row * X_COLS);
    float4 q0 = xv[tid];
    float4 q1 = xv[tid + 256];
    float s = fabsf(q0.x) + fabsf(q0.y) + fabsf(q0.z) + fabsf(q0.w)
            + fabsf(q1.x) + fabsf(q1.y) + fabsf(q1.z) + fabsf(q1.w);
    #pragma unroll
    for (int off = 32; off > 0; off >>= 1) s += __shfl_down(s, off, 64);
    __shared__ float ls[4];
    __shared__ float scale_sh;
    int wave = tid >> 6, lane = tid & 63;
    if (lane == 0) ls[wave] = s;
    __syncthreads();
    if (tid == 0) {
        float t = (ls[0] + ls[1] + ls[2] + ls[3]) * (1.0f / (float)X_COLS);
        scale_sh = t;
        scale_out[row] = t;
    }
    __syncthreads();
    float sc = scale_sh;

    float4 n0, n1;
    n0.x = -2.0f * (q0.x / sc); n0.y = -2.0f * (q0.y / sc);
    n0.z = -2.0f * (q0.z / sc); n0.w = -2.0f * (q0.w / sc);
    n1.x = -2.0f * (q1.x / sc); n1.y = -2.0f * (q1.y / sc);
    n1.z = -2.0f * (q1.z / sc); n1.w = -2.0f * (q1.w / sc);
    float4* nv = (float4*)(nu_out + row * X_COLS);
    nv[tid] = n0;
    nv[tid + 256] = n1;
}

// ---------------- argmin: 8 rows/block, 512 blocks, pinned prefetch -------
// nu via block-uniform loads -> s_load -> SGPR-resident (verified r7).
// History of the prefetch fight: r7/r8 the scheduler SANK the prefetch
// loads to their uses (VGPR 36/32) -> latency-bound ~110 µs. The
// sched_barrier(0) after the loads forbids sinking: results stay live
// across the 192-instr compute block, giving true double-buffering.
__global__ __launch_bounds__(256, 2) void argmin_kernel(const float* __restrict__ cb,
                                                        const float* __restrict__ nu_g,
                                                        int* __restrict__ indices) {
    int tid = threadIdx.x;
    int m0 = blockIdx.x * RPB;

    const float* nup = nu_g + (size_t)m0 * CB_DIM;     // block-uniform
    float nu[RPB * CB_DIM];
    #pragma unroll
    for (int i = 0; i < RPB * CB_DIM; i++) nu[i] = nup[i];

    float best[RPB];
    int   bidx[RPB];
    #pragma unroll
    for (int r = 0; r < RPB; r++) { best[r] = 3.4e38f; bidx[r] = 0; }

    // ---- hot loop: 2 codes/iter, prefetch pinned above compute ----
    const float4* cp = (const float4*)cb;
    float4 a0 = cp[2 * tid],             a1 = cp[2 * tid + 1];
    float4 b0 = cp[2 * (tid + THREADS)], b1 = cp[2 * (tid + THREADS) + 1];

    int n = tid;
    for (int k = 0; k < 127; k++, n += 2 * THREADS) {
        float4 pa0 = cp[2 * (n + 2 * THREADS)], pa1 = cp[2 * (n + 2 * THREADS) + 1];
        float4 pb0 = cp[2 * (n + 3 * THREADS)], pb1 = cp[2 * (n + 3 * THREADS) + 1];
        __builtin_amdgcn_sched_barrier(0);             // loads may not sink below
        CODE_BODY(a0, a1, n)
        CODE_BODY(b0, b1, n + THREADS)
        a0 = pa0; a1 = pa1; b0 = pb0; b1 = pb1;
    }
    CODE_BODY(a0, a1, n)
    CODE_BODY(b0, b1, n + THREADS)

    // ---- cross-thread reduce: (sortable(dist)<<32)|idx, u64-min ----
    __shared__ unsigned long long red[RPB][THREADS];   // 16 KB
    #pragma unroll
    for (int r = 0; r < RPB; r++) {
        unsigned int b = __float_as_uint(best[r]);
        unsigned int k = b ^ ((unsigned int)((int)b >> 31) | 0x80000000u);
        red[r][tid] = ((unsigned long long)k << 32) | (unsigned int)bidx[r];
    }
    for (int t = THREADS / 2; t > 0; t >>= 1) {
        __syncthreads();
        if (tid < t) {
            #pragma unroll
            for (int r = 0; r < RPB; r++) {
                unsigned long long a = red[r][tid], c = red[r][tid + t];
                if (c < a) red[r][tid] = c;
            }
        }
    }
    __syncthreads();
    if (tid < RPB) {
        indices[m0 + tid] = (int)(red[tid][0] & 0xFFFFFFFFull);
    }
}

// ---------------- finalize: segment-mean + gather + rescale ----------------
// Each output row scans all 4096 indices (LDS-resident, int4) and averages
// matching nu-rows; u-sum = -0.5 * nu-sum (pow2, exact).
// grid 256 blocks x 256: 16 rows/block, 16 threads/row, 256 indices/thread.
__global__ __launch_bounds__(256) void finalize_kernel(const int* __restrict__ indices,
                                                       const float* __restrict__ nu_g,
                                                       const float* __restrict__ scale,
                                                       float* __restrict__ out) {
    __shared__ int idx_sh[M_ROWS];                     // 16 KB
    int tid = threadIdx.x;
    {
        const int4* ig = (const int4*)indices;
        int4* is = (int4*)idx_sh;
        for (int i = tid; i < M_ROWS / 4; i += 256) is[i] = ig[i];
    }
    __syncthreads();

    int r = tid >> 4, p = tid & 15;                    // 16 rows, 16 parts
    int m = blockIdx.x * 16 + r;
    int my = idx_sh[m];

    float cnt = 0.f;
    float sum[CB_DIM];
    #pragma unroll
    for (int k = 0; k < CB_DIM; k++) sum[k] = 0.f;

    const float4* uv = (const float4*)nu_g;
    const int4* is = (const int4*)(idx_sh + p * 256);
    #pragma unroll 2
    for (int q = 0; q < 64; q++) {
        int4 w = is[q];
        int j = p * 256 + 4 * q;
        if (w.x == my) {
            float4 v0 = uv[2 * j], v1 = uv[2 * j + 1];
            cnt += 1.f;
            sum[0] += v0.x; sum[1] += v0.y; sum[2] += v0.z; sum[3] += v0.w;
            sum[4] += v1.x; sum[5] += v1.y; sum[6] += v1.z; sum[7] += v1.w;
        }
        if (w.y == my) {
            float4 v0 = uv[2 * j + 2], v1 = uv[2 * j + 3];
            cnt += 1.f;
            sum[0] += v0.x; sum[1] += v0.y; sum[2] += v0.z; sum[3] += v0.w;
            sum[4] += v1.x; sum[5] += v1.y; sum[6] += v1.z; sum[7] += v1.w;
        }
        if (w.z == my) {
            float4 v0 = uv[2 * j + 4], v1 = uv[2 * j + 5];
            cnt += 1.f;
            sum[0] += v0.x; sum[1] += v0.y; sum[2] += v0.z; sum[3] += v0.w;
            sum[4] += v1.x; sum[5] += v1.y; sum[6] += v1.z; sum[7] += v1.w;
        }
        if (w.w == my) {
            float4 v0 = uv[2 * j + 6], v1 = uv[2 * j + 7];
            cnt += 1.f;
            sum[0] += v0.x; sum[1] += v0.y; sum[2] += v0.z; sum[3] += v0.w;
            sum[4] += v1.x; sum[5] += v1.y; sum[6] += v1.z; sum[7] += v1.w;
        }
    }

    // reduce across the 16 lanes of this row (contiguous within a wave)
    #pragma unroll
    for (int off = 1; off < 16; off <<= 1) {
        cnt += __shfl_xor(cnt, off, 64);
        #pragma unroll
        for (int k = 0; k < CB_DIM; k++) sum[k] += __shfl_xor(sum[k], off, 64);
    }

    if (p == 0) {
        float c = cnt < 1.f ? 1.f : cnt;               // matches clip(counts,1)
        float sc = scale[m >> 8];
        float inv = -0.5f / c;                         // u-sum = -0.5*nu-sum
        float4 o0 = make_float4(sc * (sum[0] * inv), sc * (sum[1] * inv),
                                sc * (sum[2] * inv), sc * (sum[3] * inv));
        float4 o1 = make_float4(sc * (sum[4] * inv), sc * (sum[5] * inv),
                                sc * (sum[6] * inv), sc * (sum[7] * inv));
        float4* op = (float4*)(out + (size_t)m * CB_DIM);
        op[0] = o0;
        op[1] = o1;
    }
}

extern "C" void kernel_launch(void* const* d_in, const int* in_sizes, int n_in,
                              void* d_out, int out_size, void* d_ws, size_t ws_size,
                              hipStream_t stream) {
    const float* x  = (const float*)d_in[0];           // [16,2048]
    const float* cb = (const float*)d_in[1];           // [65536,8]
    char* ws = (char*)d_ws;
    float* scale   = (float*)(ws + WS_SCALE);
    int*   indices = (int*)(ws + WS_IDX);
    float* nu      = (float*)(ws + WS_NU);
    float* out     = (float*)d_out;

    prep_kernel    <<<B_ROWS, 256, 0, stream>>>(x, scale, nu);
    argmin_kernel  <<<M_ROWS / RPB, 256, 0, stream>>>(cb, nu, indices);
    finalize_kernel<<<M_ROWS / 16, 256, 0, stream>>>(indices, nu, scale, out);
}